// Round 3
// baseline (158.778 us; speedup 1.0000x reference)
//
#include <hip/hip_runtime.h>

// Problem constants (from reference setup_inputs).
#define BATCH  4
#define NQ     8192
#define NA     6890
#define NSPLIT 16    // anchor splits = waves per block
#define PER    432   // fallback: anchors per wave
#define NPAIR  3445  // NA/2 real anchor pairs per batch
#define NPAD   3456  // padded pairs per batch (16 waves x 216)
#define PPW    216   // pairs per wave (uniform, padded)
#define NG     108   // 2-pair groups per wave (PPW/2), compile-time constant

typedef float v2f __attribute__((ext_vector_type(2)));

// ---------------------------------------------------------------------------
// Prep: repack anchors [B][NA][3] -> padded pair-SoA [B][NPAD][8]:
// (x0,x1, y0,y1, z0,z1, h0,h1) with h = 0.5*|a|^2. Pad pairs get h=1e30 so
// their score keys can never win the argmin. Uniform 216 pairs per wave.
// ---------------------------------------------------------------------------
__global__ void repack_kernel(const float* __restrict__ anchor,
                              float* __restrict__ packed) {
    const int t = blockIdx.x * blockDim.x + threadIdx.x;
    if (t >= BATCH * NPAD) return;
    const int b = t / NPAD, p = t - b * NPAD;
    float* d = packed + ((size_t)b * NPAD + p) * 8;
    if (p < NPAIR) {   // NA even -> pair fully real
        const float* s = anchor + ((size_t)b * NA + 2 * (size_t)p) * 3;
        const float x0 = s[0], y0 = s[1], z0 = s[2];
        const float x1 = s[3], y1 = s[4], z1 = s[5];
        d[0] = x0; d[1] = x1;
        d[2] = y0; d[3] = y1;
        d[4] = z0; d[5] = z1;
        d[6] = 0.5f * (x0*x0 + y0*y0 + z0*z0);
        d[7] = 0.5f * (x1*x1 + y1*y1 + z1*z1);
    } else {           // sentinel pad: score = +huge, never selected
        d[0] = 0.f; d[1] = 0.f; d[2] = 0.f; d[3] = 0.f;
        d[4] = 0.f; d[5] = 0.f; d[6] = 1e30f; d[7] = 1e30f;
    }
}

// ---------------------------------------------------------------------------
// Main kernel: score = (h + hq) - q.a = 0.5*||q-a||^2 >= 0, so float bits
// order as uint; key = (bits & 0xFFFFE000) | anchor_idx (idx < 8192).
// Anchor stream via VMEM global_load (laundered pointer) so the compiler can
// pipeline with fine-grained vmcnt(N) waits — SMEM's lgkmcnt(0) full-drain
// was the round-1/2 stall. 2-pair (64 B) groups, 2-deep double buffer.
// ---------------------------------------------------------------------------
#define DECL_G(p) v2f p##0,p##1,p##2,p##3,p##4,p##5,p##6,p##7;
#define LOAD_G(p, sp) do { const v2f* _s = (sp); \
  p##0=_s[0]; p##1=_s[1]; p##2=_s[2]; p##3=_s[3]; \
  p##4=_s[4]; p##5=_s[5]; p##6=_s[6]; p##7=_s[7]; } while(0)

#define EVALS(X,Y,Z,H,idx) do { \
  const v2f _hh = (H) + hq2; \
  const v2f _s = __builtin_elementwise_fma((X), nqx, \
                   __builtin_elementwise_fma((Y), nqy, \
                     __builtin_elementwise_fma((Z), nqz, _hh))); \
  const unsigned _kA = (__float_as_uint(_s.x) & 0xFFFFE000u) | (unsigned)(idx); \
  const unsigned _kB = (__float_as_uint(_s.y) & 0xFFFFE000u) | (unsigned)((idx)+1); \
  best0 = (_kA < best0) ? _kA : best0; \
  best1 = (_kB < best1) ? _kB : best1; } while(0)

#define COMP_G(p, kk) do { \
  EVALS(p##0,p##1,p##2,p##3,(kk)); \
  EVALS(p##4,p##5,p##6,p##7,(kk)+2); } while(0)

__global__ __launch_bounds__(NSPLIT * 64)
void collision_dot_kernel(const float* __restrict__ query,
                          const float* __restrict__ packed,
                          const float* __restrict__ anchor,
                          const float* __restrict__ normals,
                          float* __restrict__ out) {
    __shared__ unsigned s_key[NSPLIT][64];

    const int lane = threadIdx.x & 63;
    const int wave = __builtin_amdgcn_readfirstlane((int)(threadIdx.x >> 6));
    const int blocksPerBatch = NQ / 64;                   // 128
    const int b = blockIdx.x / blocksPerBatch;
    const int q = (blockIdx.x % blocksPerBatch) * 64 + lane;

    const float* qp = query + ((size_t)b * NQ + q) * 3;
    const float qx = qp[0], qy = qp[1], qz = qp[2];
    const float hq = 0.5f * (qx*qx + qy*qy + qz*qz);
    const v2f nqx = {-qx,-qx}, nqy = {-qy,-qy}, nqz = {-qz,-qz};
    const v2f hq2 = {hq, hq};

    // Opaque VGPR zero: defeats uniformity analysis so the anchor stream is
    // VMEM (global_load, precise vmcnt(N) waits), not SMEM (lgkmcnt(0) drain).
    int zoff;
    asm volatile("v_mov_b32 %0, 0" : "=v"(zoff));

    const int k0 = wave * (2 * PPW);                      // anchor index base
    const float* Pf = packed + ((size_t)b * NPAD + (size_t)wave * PPW) * 8
                             + (size_t)(unsigned)zoff;
    const v2f* __restrict__ Pv = (const v2f*)Pf;

    unsigned best0 = 0xFFFFFFFFu, best1 = 0xFFFFFFFFu;

    DECL_G(c) DECL_G(t)
    LOAD_G(c, Pv);
    int g = 0;
    #pragma clang loop unroll(disable)
    while (g + 2 < NG) {
        LOAD_G(t, Pv + 8 * (g + 1));
        COMP_G(c, k0 + 4 * g);
        LOAD_G(c, Pv + 8 * (g + 2));
        COMP_G(t, k0 + 4 * (g + 1));
        g += 2;
    }
    // g == NG-2: two groups remain.
    LOAD_G(t, Pv + 8 * (NG - 1));
    COMP_G(c, k0 + 4 * (NG - 2));
    COMP_G(t, k0 + 4 * (NG - 1));

    s_key[wave][lane] = (best1 < best0) ? best1 : best0;
    __syncthreads();

    if (threadIdx.x < 64) {
        unsigned bk = s_key[0][lane];
        #pragma unroll
        for (int s = 1; s < NSPLIT; ++s) {
            const unsigned v = s_key[s][lane];
            bk = (v < bk) ? v : bk;
        }
        const int bidx = (int)(bk & 8191u);
        // Recompute exact d2 / dot for the selected NN (direct-diff form).
        const float* A = anchor + (size_t)b * NA * 3;
        const float* ap = A + (size_t)bidx * 3;
        const float* npnt = normals + ((size_t)b * NA + bidx) * 3;
        const float dx = qx - ap[0], dy = qy - ap[1], dz = qz - ap[2];
        const float d2  = fmaf(dz, dz, fmaf(dy, dy, dx * dx));
        const float dot = fmaf(dz, npnt[2], fmaf(dy, npnt[1], dx * npnt[0]));
        // dot * (l2 <= 0.5) < 0  <=>  dot < 0 && d2 <= 0.25
        const bool coll = (dot < 0.0f) && (d2 <= 0.25f);
        const unsigned long long m = __ballot(coll);
        if (lane == 0) atomicAdd(out + b, (float)__popcll(m));
    }
}

// ---------------------------------------------------------------------------
// Fallback (round-0 scalar kernel, verbatim) if workspace is too small.
// ---------------------------------------------------------------------------
#define DECL_BUF(p) \
  float p##00,p##01,p##02,p##03,p##04,p##05,p##06,p##07, \
        p##08,p##09,p##10,p##11,p##12,p##13,p##14,p##15, \
        p##16,p##17,p##18,p##19,p##20,p##21,p##22,p##23;

#define LOAD_BUF(p, sp) do { const float* _s = (sp); \
  p##00=_s[0];  p##01=_s[1];  p##02=_s[2];  p##03=_s[3]; \
  p##04=_s[4];  p##05=_s[5];  p##06=_s[6];  p##07=_s[7]; \
  p##08=_s[8];  p##09=_s[9];  p##10=_s[10]; p##11=_s[11]; \
  p##12=_s[12]; p##13=_s[13]; p##14=_s[14]; p##15=_s[15]; \
  p##16=_s[16]; p##17=_s[17]; p##18=_s[18]; p##19=_s[19]; \
  p##20=_s[20]; p##21=_s[21]; p##22=_s[22]; p##23=_s[23]; } while(0)

#define EVAL1(ax,ay,az,idx,acc) do { \
  const float _dx = qx-(ax), _dy = qy-(ay), _dz = qz-(az); \
  const float _d  = fmaf(_dz,_dz, fmaf(_dy,_dy, _dx*_dx)); \
  const unsigned _key = (__float_as_uint(_d) & 0xFFFFE000u) | (unsigned)(idx); \
  acc = (_key < acc) ? _key : acc; } while(0)

#define COMP_BUF(p, kk) do { \
  EVAL1(p##00,p##01,p##02,(kk)+0,best0); \
  EVAL1(p##03,p##04,p##05,(kk)+1,best1); \
  EVAL1(p##06,p##07,p##08,(kk)+2,best0); \
  EVAL1(p##09,p##10,p##11,(kk)+3,best1); \
  EVAL1(p##12,p##13,p##14,(kk)+4,best0); \
  EVAL1(p##15,p##16,p##17,(kk)+5,best1); \
  EVAL1(p##18,p##19,p##20,(kk)+6,best0); \
  EVAL1(p##21,p##22,p##23,(kk)+7,best1); } while(0)

__global__ __launch_bounds__(NSPLIT * 64)
void collision_kernel(const float* __restrict__ query,
                      const float* __restrict__ anchor,
                      const float* __restrict__ normals,
                      float* __restrict__ out) {
    __shared__ unsigned s_key[NSPLIT][64];

    const int lane = threadIdx.x & 63;
    const int wave = __builtin_amdgcn_readfirstlane((int)(threadIdx.x >> 6));
    const int blocksPerBatch = NQ / 64;                   // 128
    const int b = blockIdx.x / blocksPerBatch;
    const int q = (blockIdx.x % blocksPerBatch) * 64 + lane;

    const float* qp = query + ((size_t)b * NQ + q) * 3;
    const float qx = qp[0], qy = qp[1], qz = qp[2];

    const float* __restrict__ A = anchor + (size_t)b * NA * 3;

    const int k0 = wave * PER;
    const int k1 = (k0 + PER < NA) ? (k0 + PER) : NA;
    const int n  = k1 - k0;
    const float* __restrict__ P = A + (size_t)3 * k0;

    unsigned best0 = 0xFFFFFFFFu, best1 = 0xFFFFFFFFu;

    const int ng = n >> 3;
    DECL_BUF(c) DECL_BUF(t)
    if (ng >= 2) {
        LOAD_BUF(c, P);
        int g = 0;
        while (g + 2 < ng) {
            LOAD_BUF(t, P + 24 * (g + 1));
            COMP_BUF(c, k0 + 8 * g);
            LOAD_BUF(c, P + 24 * (g + 2));
            COMP_BUF(t, k0 + 8 * (g + 1));
            g += 2;
        }
        if (g + 1 < ng) {
            LOAD_BUF(t, P + 24 * (g + 1));
            COMP_BUF(c, k0 + 8 * g);
            COMP_BUF(t, k0 + 8 * (g + 1));
        } else {
            COMP_BUF(c, k0 + 8 * g);
        }
    } else if (ng == 1) {
        LOAD_BUF(c, P);
        COMP_BUF(c, k0);
    }
    for (int k = ng << 3; k < n; ++k) {
        EVAL1(P[3*k+0], P[3*k+1], P[3*k+2], k0 + k, best0);
    }

    s_key[wave][lane] = (best1 < best0) ? best1 : best0;
    __syncthreads();

    if (threadIdx.x < 64) {
        unsigned bk = s_key[0][lane];
        #pragma unroll
        for (int s = 1; s < NSPLIT; ++s) {
            const unsigned v = s_key[s][lane];
            bk = (v < bk) ? v : bk;
        }
        const int bidx = (int)(bk & 8191u);
        const float* ap = A + (size_t)bidx * 3;
        const float* npnt = normals + ((size_t)b * NA + bidx) * 3;
        const float dx = qx - ap[0], dy = qy - ap[1], dz = qz - ap[2];
        const float d2  = fmaf(dz, dz, fmaf(dy, dy, dx * dx));
        const float dot = fmaf(dz, npnt[2], fmaf(dy, npnt[1], dx * npnt[0]));
        const bool coll = (dot < 0.0f) && (d2 <= 0.25f);
        const unsigned long long m = __ballot(coll);
        if (lane == 0) atomicAdd(out + b, (float)__popcll(m));
    }
}

extern "C" void kernel_launch(void* const* d_in, const int* in_sizes, int n_in,
                              void* d_out, int out_size, void* d_ws, size_t ws_size,
                              hipStream_t stream) {
    const float* query   = (const float*)d_in[0];
    const float* anchor  = (const float*)d_in[1];
    const float* normals = (const float*)d_in[2];
    float* out = (float*)d_out;

    // d_out is poisoned with 0xAA before every call — zero it (graph-safe).
    hipMemsetAsync(d_out, 0, (size_t)out_size * sizeof(float), stream);

    const size_t WS_NEED = (size_t)BATCH * NPAD * 8 * sizeof(float);  // ~432 KB

    if (d_ws && ws_size >= WS_NEED) {
        float* packed = (float*)d_ws;
        const int pthreads = BATCH * NPAD;
        repack_kernel<<<dim3((pthreads + 255) / 256), dim3(256), 0, stream>>>(anchor, packed);
        const int grid = BATCH * (NQ / 64);    // 512 blocks x 1024 threads
        collision_dot_kernel<<<dim3(grid), dim3(NSPLIT * 64), 0, stream>>>(
            query, packed, anchor, normals, out);
    } else {
        const int grid = BATCH * (NQ / 64);
        collision_kernel<<<dim3(grid), dim3(NSPLIT * 64), 0, stream>>>(
            query, anchor, normals, out);
    }
}

// Round 4
// 99.715 us; speedup vs baseline: 1.5923x; 1.5923x over previous
//
#include <hip/hip_runtime.h>

// Problem constants (from reference setup_inputs).
#define BATCH  4
#define NQ     8192
#define NA     6890
#define NPAIR  3445  // real anchor pairs per batch
#define NPAD   3456  // padded pairs per batch = 2 halves x 1728
#define HALF   1728  // pairs per block (one half), = 16 waves x 108
#define PPW    108   // pairs per wave in main kernel
#define QPB    128   // queries per block (2 per thread)
#define NWAVE  16

typedef float v2f __attribute__((ext_vector_type(2)));

// ---------------------------------------------------------------------------
// Prep: repack anchors [B][NA][3] -> padded pair-SoA [B][NPAD][8]:
// (x0,x1, y0,y1, z0,z1, h0,h1) with h = 0.5*|a|^2. Pad pairs get h=1e30 so
// their keys can never win the argmin.
// ---------------------------------------------------------------------------
__global__ void repack_kernel(const float* __restrict__ anchor,
                              float* __restrict__ packed) {
    const int t = blockIdx.x * blockDim.x + threadIdx.x;
    if (t >= BATCH * NPAD) return;
    const int b = t / NPAD, p = t - b * NPAD;
    float* d = packed + ((size_t)b * NPAD + p) * 8;
    if (p < NPAIR) {   // NA even -> pair fully real
        const float* s = anchor + ((size_t)b * NA + 2 * (size_t)p) * 3;
        const float x0 = s[0], y0 = s[1], z0 = s[2];
        const float x1 = s[3], y1 = s[4], z1 = s[5];
        d[0] = x0; d[1] = x1;
        d[2] = y0; d[3] = y1;
        d[4] = z0; d[5] = z1;
        d[6] = 0.5f * (x0*x0 + y0*y0 + z0*z0);
        d[7] = 0.5f * (x1*x1 + y1*y1 + z1*z1);
    } else {           // sentinel pad: score = +huge, never selected
        d[0] = 0.f; d[1] = 0.f; d[2] = 0.f; d[3] = 0.f;
        d[4] = 0.f; d[5] = 0.f; d[6] = 1e30f; d[7] = 1e30f;
    }
}

// ---------------------------------------------------------------------------
// Main kernel: anchors staged in LDS (off the global-memory port), read via
// same-address ds_read_b128 broadcast with fine-grained lgkmcnt waits.
// Block = 16 waves; covers 128 queries (2/thread) x one half of the anchors.
// Wave w scans its private 108-pair slab. Argmin key = (score bits & mask)|idx,
// score = h + hq - q.a = 0.5*||q-a||^2 >= 0 (uint-orderable, 13-bit idx).
// Cross-block combine via per-query atomicMin into the keys array.
// ---------------------------------------------------------------------------
__global__ __launch_bounds__(1024, 8)
void collision_lds_kernel(const float* __restrict__ query,
                          const float* __restrict__ packed,
                          unsigned* __restrict__ keys) {
    __shared__ union {
        float4   st[HALF * 2];        // 1728 pairs x 32 B = 55296 B
        unsigned key[NWAVE][QPB];     // 8 KB overlay for the block reduction
    } sh;

    const int tid  = threadIdx.x;
    const int lane = tid & 63;
    const int wave = __builtin_amdgcn_readfirstlane(tid >> 6);
    const int qg = blockIdx.x >> 1;        // query-group (128 queries each)
    const int s  = blockIdx.x & 1;         // which anchor half
    const int b  = qg >> 6;                // 64 query-groups per batch
    const int qbase = (qg & 63) * QPB;

    // Stage this block's 1728 packed pairs into LDS (coalesced float4 copy).
    const float4* src = (const float4*)(packed
                        + ((size_t)b * NPAD + (size_t)s * HALF) * 8);
    #pragma unroll
    for (int i = tid; i < HALF * 2; i += 1024) sh.st[i] = src[i];

    // Per-thread queries (lane and lane+64 of the query-group).
    const float* qp0 = query + ((size_t)b * NQ + qbase + lane) * 3;
    const float* qp1 = qp0 + 64 * 3;
    const float q0x = qp0[0], q0y = qp0[1], q0z = qp0[2];
    const float q1x = qp1[0], q1y = qp1[1], q1z = qp1[2];
    const v2f nq0x = {-q0x,-q0x}, nq0y = {-q0y,-q0y}, nq0z = {-q0z,-q0z};
    const v2f nq1x = {-q1x,-q1x}, nq1y = {-q1y,-q1y}, nq1z = {-q1z,-q1z};
    const float hq0 = 0.5f * (q0x*q0x + q0y*q0y + q0z*q0z);
    const float hq1 = 0.5f * (q1x*q1x + q1y*q1y + q1z*q1z);
    const v2f hq0v = {hq0,hq0}, hq1v = {hq1,hq1};

    __syncthreads();

    const int k0 = 2 * (s * HALF + wave * PPW);   // global anchor index base
    const float4* S = sh.st + (size_t)wave * PPW * 2;

    unsigned best00 = 0xFFFFFFFFu, best01 = 0xFFFFFFFFu;
    unsigned best10 = 0xFFFFFFFFu, best11 = 0xFFFFFFFFu;

    #pragma unroll 4
    for (int p = 0; p < PPW; ++p) {
        const float4 A  = S[2*p];      // x0,x1,y0,y1
        const float4 Bq = S[2*p+1];    // z0,z1,h0,h1
        const v2f X = {A.x,  A.y},  Y = {A.z,  A.w};
        const v2f Z = {Bq.x, Bq.y}, H = {Bq.z, Bq.w};
        const unsigned idx = (unsigned)(k0 + 2*p);
        const v2f h0 = H + hq0v;
        const v2f s0 = __builtin_elementwise_fma(X, nq0x,
                         __builtin_elementwise_fma(Y, nq0y,
                           __builtin_elementwise_fma(Z, nq0z, h0)));
        const v2f h1 = H + hq1v;
        const v2f s1 = __builtin_elementwise_fma(X, nq1x,
                         __builtin_elementwise_fma(Y, nq1y,
                           __builtin_elementwise_fma(Z, nq1z, h1)));
        unsigned k;
        k = (__float_as_uint(s0.x) & 0xFFFFE000u) |  idx;      best00 = k < best00 ? k : best00;
        k = (__float_as_uint(s0.y) & 0xFFFFE000u) | (idx + 1); best01 = k < best01 ? k : best01;
        k = (__float_as_uint(s1.x) & 0xFFFFE000u) |  idx;      best10 = k < best10 ? k : best10;
        k = (__float_as_uint(s1.y) & 0xFFFFE000u) | (idx + 1); best11 = k < best11 ? k : best11;
    }

    __syncthreads();   // all waves finished reading the staged anchors
    sh.key[wave][lane]      = best01 < best00 ? best01 : best00;
    sh.key[wave][64 + lane] = best11 < best10 ? best11 : best10;
    __syncthreads();

    if (tid < QPB) {   // one atomic per query per block (2 blocks/query total)
        unsigned bk = sh.key[0][tid];
        #pragma unroll
        for (int w = 1; w < NWAVE; ++w) {
            const unsigned v = sh.key[w][tid];
            bk = v < bk ? v : bk;
        }
        atomicMin(&keys[(size_t)b * NQ + qbase + tid], bk);
    }
}

// ---------------------------------------------------------------------------
// Finalize: per query, read winning key, recompute exact d2/dot for the
// selected NN (identical math to rounds 0-3), ballot + one atomic per wave.
// ---------------------------------------------------------------------------
__global__ void finalize_kernel(const float* __restrict__ query,
                                const float* __restrict__ anchor,
                                const float* __restrict__ normals,
                                const unsigned* __restrict__ keys,
                                float* __restrict__ out) {
    const int tid = blockIdx.x * 256 + (int)threadIdx.x;
    const int b  = tid >> 13;           // 8192 queries per batch
    const int qi = tid & 8191;
    const unsigned bk = keys[tid];
    const int bidx = (int)(bk & 8191u);
    const float* qp = query   + ((size_t)b * NQ + qi)   * 3;
    const float* ap = anchor  + ((size_t)b * NA + bidx) * 3;
    const float* np2 = normals + ((size_t)b * NA + bidx) * 3;
    const float qx = qp[0], qy = qp[1], qz = qp[2];
    const float dx = qx - ap[0], dy = qy - ap[1], dz = qz - ap[2];
    const float d2  = fmaf(dz, dz, fmaf(dy, dy, dx * dx));
    const float dot = fmaf(dz, np2[2], fmaf(dy, np2[1], dx * np2[0]));
    // dot * (l2 <= 0.5) < 0  <=>  dot < 0 && d2 <= 0.25
    const bool coll = (dot < 0.0f) && (d2 <= 0.25f);
    const unsigned long long m = __ballot(coll);
    if ((threadIdx.x & 63) == 0) atomicAdd(out + b, (float)__popcll(m));
}

// ---------------------------------------------------------------------------
// Fallback (round-0 scalar kernel, verbatim) if workspace is too small.
// ---------------------------------------------------------------------------
#define NSPLIT 16
#define PER    432

#define DECL_BUF(p) \
  float p##00,p##01,p##02,p##03,p##04,p##05,p##06,p##07, \
        p##08,p##09,p##10,p##11,p##12,p##13,p##14,p##15, \
        p##16,p##17,p##18,p##19,p##20,p##21,p##22,p##23;

#define LOAD_BUF(p, sp) do { const float* _s = (sp); \
  p##00=_s[0];  p##01=_s[1];  p##02=_s[2];  p##03=_s[3]; \
  p##04=_s[4];  p##05=_s[5];  p##06=_s[6];  p##07=_s[7]; \
  p##08=_s[8];  p##09=_s[9];  p##10=_s[10]; p##11=_s[11]; \
  p##12=_s[12]; p##13=_s[13]; p##14=_s[14]; p##15=_s[15]; \
  p##16=_s[16]; p##17=_s[17]; p##18=_s[18]; p##19=_s[19]; \
  p##20=_s[20]; p##21=_s[21]; p##22=_s[22]; p##23=_s[23]; } while(0)

#define EVAL1(ax,ay,az,idx,acc) do { \
  const float _dx = qx-(ax), _dy = qy-(ay), _dz = qz-(az); \
  const float _d  = fmaf(_dz,_dz, fmaf(_dy,_dy, _dx*_dx)); \
  const unsigned _key = (__float_as_uint(_d) & 0xFFFFE000u) | (unsigned)(idx); \
  acc = (_key < acc) ? _key : acc; } while(0)

#define COMP_BUF(p, kk) do { \
  EVAL1(p##00,p##01,p##02,(kk)+0,best0); \
  EVAL1(p##03,p##04,p##05,(kk)+1,best1); \
  EVAL1(p##06,p##07,p##08,(kk)+2,best0); \
  EVAL1(p##09,p##10,p##11,(kk)+3,best1); \
  EVAL1(p##12,p##13,p##14,(kk)+4,best0); \
  EVAL1(p##15,p##16,p##17,(kk)+5,best1); \
  EVAL1(p##18,p##19,p##20,(kk)+6,best0); \
  EVAL1(p##21,p##22,p##23,(kk)+7,best1); } while(0)

__global__ __launch_bounds__(NSPLIT * 64)
void collision_kernel(const float* __restrict__ query,
                      const float* __restrict__ anchor,
                      const float* __restrict__ normals,
                      float* __restrict__ out) {
    __shared__ unsigned s_key[NSPLIT][64];

    const int lane = threadIdx.x & 63;
    const int wave = __builtin_amdgcn_readfirstlane((int)(threadIdx.x >> 6));
    const int blocksPerBatch = NQ / 64;                   // 128
    const int b = blockIdx.x / blocksPerBatch;
    const int q = (blockIdx.x % blocksPerBatch) * 64 + lane;

    const float* qp = query + ((size_t)b * NQ + q) * 3;
    const float qx = qp[0], qy = qp[1], qz = qp[2];

    const float* __restrict__ A = anchor + (size_t)b * NA * 3;

    const int k0 = wave * PER;
    const int k1 = (k0 + PER < NA) ? (k0 + PER) : NA;
    const int n  = k1 - k0;
    const float* __restrict__ P = A + (size_t)3 * k0;

    unsigned best0 = 0xFFFFFFFFu, best1 = 0xFFFFFFFFu;

    const int ng = n >> 3;
    DECL_BUF(c) DECL_BUF(t)
    if (ng >= 2) {
        LOAD_BUF(c, P);
        int g = 0;
        while (g + 2 < ng) {
            LOAD_BUF(t, P + 24 * (g + 1));
            COMP_BUF(c, k0 + 8 * g);
            LOAD_BUF(c, P + 24 * (g + 2));
            COMP_BUF(t, k0 + 8 * (g + 1));
            g += 2;
        }
        if (g + 1 < ng) {
            LOAD_BUF(t, P + 24 * (g + 1));
            COMP_BUF(c, k0 + 8 * g);
            COMP_BUF(t, k0 + 8 * (g + 1));
        } else {
            COMP_BUF(c, k0 + 8 * g);
        }
    } else if (ng == 1) {
        LOAD_BUF(c, P);
        COMP_BUF(c, k0);
    }
    for (int k = ng << 3; k < n; ++k) {
        EVAL1(P[3*k+0], P[3*k+1], P[3*k+2], k0 + k, best0);
    }

    s_key[wave][lane] = (best1 < best0) ? best1 : best0;
    __syncthreads();

    if (threadIdx.x < 64) {
        unsigned bk = s_key[0][lane];
        #pragma unroll
        for (int s = 1; s < NSPLIT; ++s) {
            const unsigned v = s_key[s][lane];
            bk = (v < bk) ? v : bk;
        }
        const int bidx = (int)(bk & 8191u);
        const float* ap = A + (size_t)bidx * 3;
        const float* npnt = normals + ((size_t)b * NA + bidx) * 3;
        const float dx = qx - ap[0], dy = qy - ap[1], dz = qz - ap[2];
        const float d2  = fmaf(dz, dz, fmaf(dy, dy, dx * dx));
        const float dot = fmaf(dz, npnt[2], fmaf(dy, npnt[1], dx * npnt[0]));
        const bool coll = (dot < 0.0f) && (d2 <= 0.25f);
        const unsigned long long m = __ballot(coll);
        if (lane == 0) atomicAdd(out + b, (float)__popcll(m));
    }
}

extern "C" void kernel_launch(void* const* d_in, const int* in_sizes, int n_in,
                              void* d_out, int out_size, void* d_ws, size_t ws_size,
                              hipStream_t stream) {
    const float* query   = (const float*)d_in[0];
    const float* anchor  = (const float*)d_in[1];
    const float* normals = (const float*)d_in[2];
    float* out = (float*)d_out;

    // d_out is poisoned with 0xAA before every call — zero it (graph-safe).
    hipMemsetAsync(d_out, 0, (size_t)out_size * sizeof(float), stream);

    const size_t PACKED_BYTES = (size_t)BATCH * NPAD * 8 * sizeof(float); // 442368
    const size_t KEYS_BYTES   = (size_t)BATCH * NQ * sizeof(unsigned);    // 131072
    const size_t WS_NEED      = PACKED_BYTES + KEYS_BYTES;                // ~573 KB

    if (d_ws && ws_size >= WS_NEED) {
        float*    packed = (float*)d_ws;
        unsigned* keys   = (unsigned*)((char*)d_ws + PACKED_BYTES);

        // keys init to UINT_MAX for atomicMin combine.
        hipMemsetAsync(keys, 0xFF, KEYS_BYTES, stream);

        const int pthreads = BATCH * NPAD;
        repack_kernel<<<dim3((pthreads + 255) / 256), dim3(256), 0, stream>>>(anchor, packed);

        // 512 blocks x 1024 threads: 256 query-groups x 2 anchor halves.
        collision_lds_kernel<<<dim3(BATCH * (NQ / QPB) * 2), dim3(1024), 0, stream>>>(
            query, packed, keys);

        finalize_kernel<<<dim3(BATCH * NQ / 256), dim3(256), 0, stream>>>(
            query, anchor, normals, keys, out);
    } else {
        const int grid = BATCH * (NQ / 64);
        collision_kernel<<<dim3(grid), dim3(NSPLIT * 64), 0, stream>>>(
            query, anchor, normals, out);
    }
}

// Round 5
// 96.403 us; speedup vs baseline: 1.6470x; 1.0344x over previous
//
#include <hip/hip_runtime.h>

// Problem constants (from reference setup_inputs).
#define BATCH  4
#define NQ     8192
#define NA     6890
#define NPAIR  3445   // real anchor pairs per batch
#define NPAD   3456   // padded pairs per batch = 2 tiles x 1728
#define HALF   1728   // pairs per LDS tile = 8 waves x 216
#define PPW    216    // pairs per wave per tile
#define NWAVE  8      // waves per block (512 threads)

typedef float v2f __attribute__((ext_vector_type(2)));

// ---------------------------------------------------------------------------
// Single fused kernel. Block = 512 threads = 8 waves, owns 64 queries
// (1 per lane; all 8 waves share the same 64 queries, each wave scans its
// private 216-pair slab per tile). The block stages both 1728-pair anchor
// tiles into LDS sequentially, packing inline to pair-SoA float4 pairs
// (x0,x1,y0,y1)(z0,z1,h0,h1) with h = 0.5*|a|^2 (pad pairs h=1e30).
// Score = h + hq - q.a = 0.5*||q-a||^2 >= 0 -> float bits order as uint;
// key = (bits & 0xFFFFE000) | anchor_idx (idx < 8192, first-occurrence ties).
// Block-reduce keys in an LDS overlay, then exact d2/dot recompute + ballot
// + one atomicAdd per block. No workspace, no extra dispatches.
// ---------------------------------------------------------------------------
__global__ __launch_bounds__(NWAVE * 64, 4)
void collision_fused_kernel(const float* __restrict__ query,
                            const float* __restrict__ anchor,
                            const float* __restrict__ normals,
                            float* __restrict__ out) {
    __shared__ union {
        float4   st[HALF * 2];        // 1728 pairs x 32 B = 55296 B
        unsigned key[NWAVE][64];      // 2 KB overlay for the block reduction
    } sh;

    const int tid  = threadIdx.x;
    const int lane = tid & 63;
    const int wave = __builtin_amdgcn_readfirstlane(tid >> 6);
    const int blocksPerBatch = NQ / 64;        // 128
    const int b = blockIdx.x >> 7;
    const int q = (blockIdx.x & 127) * 64 + lane;

    const float* qp = query + ((size_t)b * NQ + q) * 3;
    const float qx = qp[0], qy = qp[1], qz = qp[2];
    const float hq = 0.5f * (qx*qx + qy*qy + qz*qz);
    const v2f nqx = {-qx,-qx}, nqy = {-qy,-qy}, nqz = {-qz,-qz};
    const v2f hqv = {hq, hq};

    const float* __restrict__ Araw = anchor + (size_t)b * NA * 3;

    unsigned best0 = 0xFFFFFFFFu, best1 = 0xFFFFFFFFu;

    #pragma unroll 1
    for (int t = 0; t < 2; ++t) {
        // ---- stage tile t: pairs [t*HALF, t*HALF+HALF) of this batch ----
        for (int p = tid; p < HALF; p += NWAVE * 64) {
            const int gp = t * HALF + p;          // pair index in [0, NPAD)
            float4 A, B;
            if (gp < NPAIR) {                     // NA even -> pair fully real
                const float* s = Araw + (size_t)6 * gp;   // 8B-aligned
                const float x0 = s[0], y0 = s[1], z0 = s[2];
                const float x1 = s[3], y1 = s[4], z1 = s[5];
                A = make_float4(x0, x1, y0, y1);
                B = make_float4(z0, z1,
                                0.5f * (x0*x0 + y0*y0 + z0*z0),
                                0.5f * (x1*x1 + y1*y1 + z1*z1));
            } else {                              // sentinel pad: never wins
                A = make_float4(0.f, 0.f, 0.f, 0.f);
                B = make_float4(0.f, 0.f, 1e30f, 1e30f);
            }
            sh.st[2*p]   = A;
            sh.st[2*p+1] = B;
        }
        __syncthreads();

        // ---- compute: this wave's private 216-pair slab ----
        const int base = wave * PPW;                  // pair offset in tile
        const int k0   = 2 * (t * HALF + base);       // global anchor index
        const float4* S = sh.st + (size_t)2 * base;

        #pragma unroll 4
        for (int p = 0; p < PPW; ++p) {
            const float4 A  = S[2*p];      // x0,x1,y0,y1  (broadcast ds_read)
            const float4 Bq = S[2*p+1];    // z0,z1,h0,h1
            const v2f X = {A.x,  A.y},  Y = {A.z,  A.w};
            const v2f Z = {Bq.x, Bq.y}, H = {Bq.z, Bq.w};
            const unsigned idx = (unsigned)(k0 + 2*p);
            const v2f h = H + hqv;
            const v2f s = __builtin_elementwise_fma(X, nqx,
                            __builtin_elementwise_fma(Y, nqy,
                              __builtin_elementwise_fma(Z, nqz, h)));
            unsigned k;
            k = (__float_as_uint(s.x) & 0xFFFFE000u) |  idx;      best0 = k < best0 ? k : best0;
            k = (__float_as_uint(s.y) & 0xFFFFE000u) | (idx + 1); best1 = k < best1 ? k : best1;
        }
        __syncthreads();   // slab reads done before restage / overlay write
    }

    // ---- block reduction: 8 partial keys per query -> winner ----
    sh.key[wave][lane] = best1 < best0 ? best1 : best0;
    __syncthreads();

    if (tid < 64) {
        unsigned bk = sh.key[0][lane];
        #pragma unroll
        for (int w = 1; w < NWAVE; ++w) {
            const unsigned v = sh.key[w][lane];
            bk = v < bk ? v : bk;
        }
        const int bidx = (int)(bk & 8191u);
        // Exact d2/dot recompute for the selected NN (direct-diff form).
        const float* ap   = Araw + (size_t)bidx * 3;
        const float* npnt = normals + ((size_t)b * NA + bidx) * 3;
        const float dx = qx - ap[0], dy = qy - ap[1], dz = qz - ap[2];
        const float d2  = fmaf(dz, dz, fmaf(dy, dy, dx * dx));
        const float dot = fmaf(dz, npnt[2], fmaf(dy, npnt[1], dx * npnt[0]));
        // dot * (l2 <= 0.5) < 0  <=>  dot < 0 && d2 <= 0.25
        const bool coll = (dot < 0.0f) && (d2 <= 0.25f);
        const unsigned long long m = __ballot(coll);
        if (lane == 0) atomicAdd(out + b, (float)__popcll(m));
    }
}

extern "C" void kernel_launch(void* const* d_in, const int* in_sizes, int n_in,
                              void* d_out, int out_size, void* d_ws, size_t ws_size,
                              hipStream_t stream) {
    const float* query   = (const float*)d_in[0];
    const float* anchor  = (const float*)d_in[1];
    const float* normals = (const float*)d_in[2];
    float* out = (float*)d_out;

    // d_out is poisoned with 0xAA before every call — zero it (graph-safe).
    hipMemsetAsync(d_out, 0, (size_t)out_size * sizeof(float), stream);

    // One fused dispatch: 512 blocks x 512 threads (2 blocks/CU, 55.3 KB LDS each).
    collision_fused_kernel<<<dim3(BATCH * (NQ / 64)), dim3(NWAVE * 64), 0, stream>>>(
        query, anchor, normals, out);
}

// Round 6
// 96.235 us; speedup vs baseline: 1.6499x; 1.0017x over previous
//
#include <hip/hip_runtime.h>

// Problem constants (from reference setup_inputs).
#define BATCH  4
#define NQ     8192
#define NA     6890
#define NPAIR  3445   // real anchor pairs per batch
#define NPAD   3456   // padded pairs per batch = 2 tiles x 1728
#define HALF   1728   // pairs per LDS tile
#define NWAVE  16     // waves per block (1024 threads)
#define QPB    128    // queries per block = 2 per thread (lane, lane+64)
#define PPT    108    // pairs per wave per tile (1728/16)

typedef float v2f __attribute__((ext_vector_type(2)));

// ---------------------------------------------------------------------------
// Single fused kernel, 2 queries per thread to halve the LDS-read traffic
// (round-5 post-mortem: kernel was 100% LDS-pipe bound at ~8 cyc per
// broadcast ds_read_b128; VALU fully hidden).
//
// Block = 1024 threads = 16 waves, owns 128 queries (each thread handles
// query lane and lane+64). Stages the two 1728-pair anchor tiles into 55.3 KB
// LDS sequentially, packing inline to pair-SoA float4 pairs
// (x0,x1,y0,y1)(z0,z1,h0,h1), h = 0.5*|a|^2 (pad pairs h=1e30).
// Per tile, wave w scans its private 108-pair slab against both queries.
// Score = h + hq - q.a = 0.5*||q-a||^2 >= 0 -> float bits order as uint;
// key = (bits & 0xFFFFE000) | anchor_idx (idx < 8192, first-occurrence ties).
// Block-reduce 16 partial keys per query in an LDS overlay, then exact
// d2/dot recompute + ballot + 2 atomicAdds per block. No workspace.
// ---------------------------------------------------------------------------
__global__ __launch_bounds__(NWAVE * 64)
void collision_fused2_kernel(const float* __restrict__ query,
                             const float* __restrict__ anchor,
                             const float* __restrict__ normals,
                             float* __restrict__ out) {
    __shared__ union {
        float4   st[HALF * 2];        // 1728 pairs x 32 B = 55296 B
        unsigned key[NWAVE][QPB];     // 8 KB overlay for the block reduction
    } sh;

    const int tid  = threadIdx.x;
    const int lane = tid & 63;
    const int wave = __builtin_amdgcn_readfirstlane(tid >> 6);
    const int b = blockIdx.x >> 6;             // 64 blocks per batch
    const int qbase = (blockIdx.x & 63) * QPB;

    // Per-thread queries: lane and lane+64 of the block's 128.
    const float* qp0 = query + ((size_t)b * NQ + qbase + lane) * 3;
    const float* qp1 = qp0 + 64 * 3;
    const float q0x = qp0[0], q0y = qp0[1], q0z = qp0[2];
    const float q1x = qp1[0], q1y = qp1[1], q1z = qp1[2];
    const float hq0 = 0.5f * (q0x*q0x + q0y*q0y + q0z*q0z);
    const float hq1 = 0.5f * (q1x*q1x + q1y*q1y + q1z*q1z);
    const v2f nq0x = {-q0x,-q0x}, nq0y = {-q0y,-q0y}, nq0z = {-q0z,-q0z};
    const v2f nq1x = {-q1x,-q1x}, nq1y = {-q1y,-q1y}, nq1z = {-q1z,-q1z};
    const v2f hq0v = {hq0,hq0}, hq1v = {hq1,hq1};

    const float* __restrict__ Araw = anchor + (size_t)b * NA * 3;

    unsigned best00 = 0xFFFFFFFFu, best01 = 0xFFFFFFFFu;   // query 0
    unsigned best10 = 0xFFFFFFFFu, best11 = 0xFFFFFFFFu;   // query 1

    #pragma unroll 1
    for (int t = 0; t < 2; ++t) {
        // ---- stage tile t: pairs [t*HALF, t*HALF+HALF) of this batch ----
        for (int p = tid; p < HALF; p += NWAVE * 64) {
            const int gp = t * HALF + p;          // pair index in [0, NPAD)
            float4 A, B;
            if (gp < NPAIR) {                     // NA even -> pair fully real
                const float* s = Araw + (size_t)6 * gp;
                const float x0 = s[0], y0 = s[1], z0 = s[2];
                const float x1 = s[3], y1 = s[4], z1 = s[5];
                A = make_float4(x0, x1, y0, y1);
                B = make_float4(z0, z1,
                                0.5f * (x0*x0 + y0*y0 + z0*z0),
                                0.5f * (x1*x1 + y1*y1 + z1*z1));
            } else {                              // sentinel pad: never wins
                A = make_float4(0.f, 0.f, 0.f, 0.f);
                B = make_float4(0.f, 0.f, 1e30f, 1e30f);
            }
            sh.st[2*p]   = A;
            sh.st[2*p+1] = B;
        }
        __syncthreads();

        // ---- compute: this wave's private 108-pair slab, both queries ----
        const int base = wave * PPT;                  // pair offset in tile
        const int k0   = 2 * (t * HALF + base);       // global anchor index
        const float4* S = sh.st + (size_t)2 * base;

        #pragma unroll 4
        for (int p = 0; p < PPT; ++p) {
            const float4 A  = S[2*p];      // x0,x1,y0,y1  (broadcast ds_read)
            const float4 Bq = S[2*p+1];    // z0,z1,h0,h1
            const v2f X = {A.x,  A.y},  Y = {A.z,  A.w};
            const v2f Z = {Bq.x, Bq.y}, H = {Bq.z, Bq.w};
            const unsigned idx = (unsigned)(k0 + 2*p);
            const v2f h0 = H + hq0v;
            const v2f s0 = __builtin_elementwise_fma(X, nq0x,
                             __builtin_elementwise_fma(Y, nq0y,
                               __builtin_elementwise_fma(Z, nq0z, h0)));
            const v2f h1 = H + hq1v;
            const v2f s1 = __builtin_elementwise_fma(X, nq1x,
                             __builtin_elementwise_fma(Y, nq1y,
                               __builtin_elementwise_fma(Z, nq1z, h1)));
            unsigned k;
            k = (__float_as_uint(s0.x) & 0xFFFFE000u) |  idx;      best00 = k < best00 ? k : best00;
            k = (__float_as_uint(s0.y) & 0xFFFFE000u) | (idx + 1); best01 = k < best01 ? k : best01;
            k = (__float_as_uint(s1.x) & 0xFFFFE000u) |  idx;      best10 = k < best10 ? k : best10;
            k = (__float_as_uint(s1.y) & 0xFFFFE000u) | (idx + 1); best11 = k < best11 ? k : best11;
        }
        __syncthreads();   // slab reads done before restage / overlay write
    }

    // ---- block reduction: 16 partial keys per query -> winner ----
    sh.key[wave][lane]      = best01 < best00 ? best01 : best00;
    sh.key[wave][64 + lane] = best11 < best10 ? best11 : best10;
    __syncthreads();

    if (tid < QPB) {       // waves 0 and 1, fully active
        unsigned bk = sh.key[0][tid];
        #pragma unroll
        for (int w = 1; w < NWAVE; ++w) {
            const unsigned v = sh.key[w][tid];
            bk = v < bk ? v : bk;
        }
        const int bidx = (int)(bk & 8191u);
        // Thread tid finalizes query qbase+tid: wave0 -> its q0, wave1 -> its q1.
        const bool hi = tid >= 64;
        const float qx = hi ? q1x : q0x;
        const float qy = hi ? q1y : q0y;
        const float qz = hi ? q1z : q0z;
        // Exact d2/dot recompute for the selected NN (direct-diff form).
        const float* ap   = Araw + (size_t)bidx * 3;
        const float* npnt = normals + ((size_t)b * NA + bidx) * 3;
        const float dx = qx - ap[0], dy = qy - ap[1], dz = qz - ap[2];
        const float d2  = fmaf(dz, dz, fmaf(dy, dy, dx * dx));
        const float dot = fmaf(dz, npnt[2], fmaf(dy, npnt[1], dx * npnt[0]));
        // dot * (l2 <= 0.5) < 0  <=>  dot < 0 && d2 <= 0.25
        const bool coll = (dot < 0.0f) && (d2 <= 0.25f);
        const unsigned long long m = __ballot(coll);
        if (lane == 0) atomicAdd(out + b, (float)__popcll(m));
    }
}

extern "C" void kernel_launch(void* const* d_in, const int* in_sizes, int n_in,
                              void* d_out, int out_size, void* d_ws, size_t ws_size,
                              hipStream_t stream) {
    const float* query   = (const float*)d_in[0];
    const float* anchor  = (const float*)d_in[1];
    const float* normals = (const float*)d_in[2];
    float* out = (float*)d_out;

    // d_out is poisoned with 0xAA before every call — zero it (graph-safe).
    hipMemsetAsync(d_out, 0, (size_t)out_size * sizeof(float), stream);

    // One fused dispatch: 256 blocks x 1024 threads (1 block/CU, 55.3 KB LDS).
    collision_fused2_kernel<<<dim3(BATCH * (NQ / QPB)), dim3(NWAVE * 64), 0, stream>>>(
        query, anchor, normals, out);
}

// Round 7
// 92.917 us; speedup vs baseline: 1.7088x; 1.0357x over previous
//
#include <hip/hip_runtime.h>

// Problem constants (from reference setup_inputs).
#define BATCH  4
#define NQ     8192
#define NA     6890
#define NPAIR  3445   // real anchor pairs per batch
#define NPAD   3456   // padded pairs per batch = 2 tiles x 1728
#define HALF   1728   // pairs per LDS tile
#define NWAVE  16     // waves per block (1024 threads)
#define PPT    108    // pairs per wave per tile (1728/16)

typedef float v2f __attribute__((ext_vector_type(2)));

// ---------------------------------------------------------------------------
// Single fused kernel, QPT=1, max occupancy (2 blocks/CU, 8 waves/SIMD).
//
// Round-6 post-mortem: duration is ~26 us VALU-issue (insts x 4 cyc fits all
// six rounds) + ~20 us latency stall; both R5 and R6 ran at 4 waves/SIMD and
// stalled identically, while the only ~stall-free round (R0) ran 8/SIMD.
// This config is the unique single-dispatch full-coverage geometry reaching
// the 32-waves/CU hardware max: 512 blocks x 16 waves, 64 queries per block,
// each wave scans a private 108-pair slab per 1728-pair LDS tile (2 tiles,
// staged sequentially, packed inline to (x0,x1,y0,y1)(z0,z1,h0,h1) with
// h = 0.5*|a|^2; pad pairs h=1e30). __launch_bounds__(1024,8) caps VGPR at
// 64 so 8 waves/SIMD is achievable. Score = h + hq - q.a = 0.5*||q-a||^2
// >= 0 -> float bits order as uint; key = (bits & 0xFFFFE000) | idx.
// Block-reduce 16 partial keys/query, exact d2/dot recompute, ballot,
// one atomicAdd. No workspace, one dispatch.
// ---------------------------------------------------------------------------
__global__ __launch_bounds__(NWAVE * 64, 8)
void collision_occ_kernel(const float* __restrict__ query,
                          const float* __restrict__ anchor,
                          const float* __restrict__ normals,
                          float* __restrict__ out) {
    __shared__ union {
        float4   st[HALF * 2];        // 1728 pairs x 32 B = 55296 B
        unsigned key[NWAVE][64];      // 4 KB overlay for the block reduction
    } sh;

    const int tid  = threadIdx.x;
    const int lane = tid & 63;
    const int wave = __builtin_amdgcn_readfirstlane(tid >> 6);
    const int b = blockIdx.x >> 7;             // 128 blocks per batch
    const int q = (blockIdx.x & 127) * 64 + lane;

    const float* qp = query + ((size_t)b * NQ + q) * 3;
    const float qx = qp[0], qy = qp[1], qz = qp[2];
    const float hq = 0.5f * (qx*qx + qy*qy + qz*qz);
    const v2f nqx = {-qx,-qx}, nqy = {-qy,-qy}, nqz = {-qz,-qz};
    const v2f hqv = {hq, hq};

    const float* __restrict__ Araw = anchor + (size_t)b * NA * 3;

    unsigned best0 = 0xFFFFFFFFu, best1 = 0xFFFFFFFFu;

    #pragma unroll 1
    for (int t = 0; t < 2; ++t) {
        // ---- stage tile t: pairs [t*HALF, t*HALF+HALF) of this batch ----
        for (int p = tid; p < HALF; p += NWAVE * 64) {
            const int gp = t * HALF + p;          // pair index in [0, NPAD)
            float4 A, B;
            if (gp < NPAIR) {                     // NA even -> pair fully real
                const float* s = Araw + (size_t)6 * gp;
                const float x0 = s[0], y0 = s[1], z0 = s[2];
                const float x1 = s[3], y1 = s[4], z1 = s[5];
                A = make_float4(x0, x1, y0, y1);
                B = make_float4(z0, z1,
                                0.5f * (x0*x0 + y0*y0 + z0*z0),
                                0.5f * (x1*x1 + y1*y1 + z1*z1));
            } else {                              // sentinel pad: never wins
                A = make_float4(0.f, 0.f, 0.f, 0.f);
                B = make_float4(0.f, 0.f, 1e30f, 1e30f);
            }
            sh.st[2*p]   = A;
            sh.st[2*p+1] = B;
        }
        __syncthreads();

        // ---- compute: this wave's private 108-pair slab ----
        const int base = wave * PPT;                  // pair offset in tile
        const int k0   = 2 * (t * HALF + base);       // global anchor index
        const float4* S = sh.st + (size_t)2 * base;

        #pragma unroll 4
        for (int p = 0; p < PPT; ++p) {
            const float4 A  = S[2*p];      // x0,x1,y0,y1  (broadcast ds_read)
            const float4 Bq = S[2*p+1];    // z0,z1,h0,h1
            const v2f X = {A.x,  A.y},  Y = {A.z,  A.w};
            const v2f Z = {Bq.x, Bq.y}, H = {Bq.z, Bq.w};
            const unsigned idx = (unsigned)(k0 + 2*p);
            const v2f h = H + hqv;
            const v2f s = __builtin_elementwise_fma(X, nqx,
                            __builtin_elementwise_fma(Y, nqy,
                              __builtin_elementwise_fma(Z, nqz, h)));
            unsigned k;
            k = (__float_as_uint(s.x) & 0xFFFFE000u) |  idx;      best0 = k < best0 ? k : best0;
            k = (__float_as_uint(s.y) & 0xFFFFE000u) | (idx + 1); best1 = k < best1 ? k : best1;
        }
        __syncthreads();   // slab reads done before restage / overlay write
    }

    // ---- block reduction: 16 partial keys per query -> winner ----
    sh.key[wave][lane] = best1 < best0 ? best1 : best0;
    __syncthreads();

    if (tid < 64) {
        unsigned bk = sh.key[0][lane];
        #pragma unroll
        for (int w = 1; w < NWAVE; ++w) {
            const unsigned v = sh.key[w][lane];
            bk = v < bk ? v : bk;
        }
        const int bidx = (int)(bk & 8191u);
        // Exact d2/dot recompute for the selected NN (direct-diff form).
        const float* ap   = Araw + (size_t)bidx * 3;
        const float* npnt = normals + ((size_t)b * NA + bidx) * 3;
        const float dx = qx - ap[0], dy = qy - ap[1], dz = qz - ap[2];
        const float d2  = fmaf(dz, dz, fmaf(dy, dy, dx * dx));
        const float dot = fmaf(dz, npnt[2], fmaf(dy, npnt[1], dx * npnt[0]));
        // dot * (l2 <= 0.5) < 0  <=>  dot < 0 && d2 <= 0.25
        const bool coll = (dot < 0.0f) && (d2 <= 0.25f);
        const unsigned long long m = __ballot(coll);
        if (lane == 0) atomicAdd(out + b, (float)__popcll(m));
    }
}

extern "C" void kernel_launch(void* const* d_in, const int* in_sizes, int n_in,
                              void* d_out, int out_size, void* d_ws, size_t ws_size,
                              hipStream_t stream) {
    const float* query   = (const float*)d_in[0];
    const float* anchor  = (const float*)d_in[1];
    const float* normals = (const float*)d_in[2];
    float* out = (float*)d_out;

    // d_out is poisoned with 0xAA before every call — zero it (graph-safe).
    hipMemsetAsync(d_out, 0, (size_t)out_size * sizeof(float), stream);

    // One fused dispatch: 512 blocks x 1024 threads
    // (2 blocks/CU, 110.6 KB LDS/CU, 32 waves/CU = 8 waves/SIMD).
    collision_occ_kernel<<<dim3(BATCH * (NQ / 64)), dim3(NWAVE * 64), 0, stream>>>(
        query, anchor, normals, out);
}